// Round 16
// baseline (69.960 us; speedup 1.0000x reference)
//
#include <hip/hip_runtime.h>

// VectorQuantizer on MI355X (gfx950) — single-pass fp16 MFMA scan + exact rescore.
// Round 15: total threads were the occupancy cap (2 lanes/px = 50% ceiling).
// One 16-px tile per WAVE (was two): 8192 waves = 8 waves/SIMD potential.
// 1024-thr blocks (16 waves, 256 px) x 512, LDS 70KB -> 2 blocks/CU = 32
// waves/CU. launch_bounds(1024,8) caps VGPR at 64 (allocator's natural pick).
// Simplifications: no candidate handoff (lane rescores own 3; pixel's 4 lanes
// butterfly-merge via xor16/32); top-3 insert via v_med3_u32 (3 ops vs 5).
// Candidate set per pixel and exact-rescore arithmetic identical to round 12.

#define C_DIM   64
#define N_EMB   512
#define HW      4096
#define N_PIX   (32 * HW)            // 131072
#define ZQ_OFF  1
#define IDX_OFF (1 + N_PIX * C_DIM)
#define NBLK    512                  // 256 px per block
#define TPB     1024                 // 16 waves x 16 px

typedef _Float16 half8 __attribute__((ext_vector_type(8)));
typedef float    f32x4 __attribute__((ext_vector_type(4)));
union FragH { unsigned u[4]; half8 h8; uint4 u4; _Float16 h[8]; };

__device__ __forceinline__ unsigned umn(unsigned a, unsigned b){ return a<b?a:b; }
__device__ __forceinline__ unsigned med3u(unsigned a, unsigned b, unsigned c){
    unsigned r;
    asm("v_med3_u32 %0, %1, %2, %3" : "=v"(r) : "v"(a), "v"(b), "v"(c));
    return r;
}

__global__ __launch_bounds__(TPB, 8) void vq_main(
    const float* __restrict__ z,
    const float* __restrict__ cb,
    float* __restrict__ out,
    float* __restrict__ ws)
{
    __shared__ unsigned cbh[N_EMB * 32];   // 64KB codebook as fp16 pairs (e*512), swizzled
    __shared__ float    esh5[N_EMB];       // esum + 0.5 (scan keys, positive d)
    __shared__ float    eshx[N_EMB];       // numpy-exact esum (rescore)
    __shared__ float    wsum[16];

    const int t = threadIdx.x;             // 0..1023

    // ---- Stage codebook (threads 0..511: thread t owns code row t) ----
    if (t < N_EMB) {
        const float* e = cb + t * C_DIM;
        float ev[64];
        #pragma unroll
        for (int q = 0; q < 16; ++q) {
            float4 v = ((const float4*)e)[q];
            ev[4*q+0]=v.x; ev[4*q+1]=v.y; ev[4*q+2]=v.z; ev[4*q+3]=v.w;
        }
        // numpy pairwise_sum(n=64): 8 accs, rounded mul, tree combine
        float r[8];
        #pragma unroll
        for (int i = 0; i < 8; ++i) r[i] = __fmul_rn(ev[i], ev[i]);
        #pragma unroll
        for (int k = 8; k < 64; k += 8) {
            #pragma unroll
            for (int i = 0; i < 8; ++i)
                r[i] = __fadd_rn(r[i], __fmul_rn(ev[k+i], ev[k+i]));
        }
        float es = __fadd_rn(
            __fadd_rn(__fadd_rn(r[0],r[1]), __fadd_rn(r[2],r[3])),
            __fadd_rn(__fadd_rn(r[4],r[5]), __fadd_rn(r[6],r[7])));
        eshx[t] = es;
        esh5[t] = es + 0.5f;
        unsigned hw_[32];
        #pragma unroll
        for (int w2 = 0; w2 < 32; ++w2) {
            union { _Float16 h[2]; unsigned u; } pk;
            pk.h[0] = (_Float16)(ev[2*w2]   * 512.0f);
            pk.h[1] = (_Float16)(ev[2*w2+1] * 512.0f);
            hw_[w2] = pk.u;
        }
        const int rs = t & 7;
        #pragma unroll
        for (int g = 0; g < 8; ++g) {
            int g2 = g ^ rs;
            *(uint4*)&cbh[t*32 + g2*4] =
                make_uint4(hw_[4*g], hw_[4*g+1], hw_[4*g+2], hw_[4*g+3]);
        }
    }
    __syncthreads();

    const int l   = t & 63;
    const int wv  = t >> 6;                // wave 0..15
    const int lg  = l >> 4;                // k-chunk / candidate group 0..3
    const int li  = l & 15;                // pixel col / code row in tile
    const int bb  = blockIdx.x >> 4;       // batch (256 px per block, 4096 per b)
    const int g20 = (lg)     ^ (li & 7);   // swizzled granule, k-step 0
    const int g21 = (4 + lg) ^ (li & 7);   // swizzled granule, k-step 1
    const int jb  = lg * 4;
    float ls = 0.f;

    // ---- This wave's single 16-px tile; lane's pixel = base + li ----
    const int pxw = blockIdx.x * 256 + wv * 16 + li;
    const float* zb = z + (size_t)bb * (C_DIM * HW) + (pxw & (HW - 1));

    // B-fragments: z as fp16, lane supplies c = s*32 + lg*8 + i
    FragH b0, b1;
    {
        const float* c0 = zb + (size_t)(lg*8) * HW;
        const float* c1 = zb + (size_t)(32 + lg*8) * HW;
        #pragma unroll
        for (int i = 0; i < 8; ++i) {
            b0.h[i] = (_Float16)c0[(size_t)i*HW];
            b1.h[i] = (_Float16)c1[(size_t)i*HW];
        }
    }

    // ---- MFMA scan: 32 code-tiles; per-lane top-3 keys (med3 insert) ----
    unsigned k1 = 0xFFFFFFFFu, k2 = 0xFFFFFFFFu, k3 = 0xFFFFFFFFu;
    #pragma unroll 4
    for (int T = 0; T < 32; ++T) {
        const int row = T*16 + li;
        FragH a0, a1;
        a0.u4 = *(const uint4*)&cbh[row*32 + g20*4];
        a1.u4 = *(const uint4*)&cbh[row*32 + g21*4];
        f32x4 es = *(const f32x4*)&esh5[T*16 + jb];
        f32x4 acc = {0.f,0.f,0.f,0.f};
        acc = __builtin_amdgcn_mfma_f32_16x16x32_f16(a0.h8, b0.h8, acc, 0,0,0);
        acc = __builtin_amdgcn_mfma_f32_16x16x32_f16(a1.h8, b1.h8, acc, 0,0,0);
        const int jT = T*16 + jb;
        #pragma unroll
        for (int r2 = 0; r2 < 4; ++r2) {
            float d = __fmaf_rn(-0.00390625f, acc[r2], es[r2]);   // >0 -> sortable
            unsigned key = (__float_as_uint(d) & 0xFFFFFE00u) | (unsigned)(jT + r2);
            unsigned nk3 = med3u(key, k2, k3);     // top-3 insert: 3 ops
            unsigned nk2 = med3u(key, k1, k2);
            k1 = umn(k1, key); k2 = nk2; k3 = nk3;
        }
    }

    // ---- rescore: every lane handles its own 3 candidates (no handoff) ----
    // zr reload: 4-way lane broadcast (lanes lg0-3 share li -> same address)
    float zr[64];
    #pragma unroll
    for (int c = 0; c < 64; ++c) zr[c] = zb[(size_t)c * HW];
    float ap;
    {   // numpy-exact ||z||^2
        float r[8];
        #pragma unroll
        for (int i = 0; i < 8; ++i) r[i] = __fmul_rn(zr[i], zr[i]);
        #pragma unroll
        for (int k = 8; k < 64; k += 8) {
            #pragma unroll
            for (int i = 0; i < 8; ++i)
                r[i] = __fadd_rn(r[i], __fmul_rn(zr[k+i], zr[k+i]));
        }
        ap = __fadd_rn(
            __fadd_rn(__fadd_rn(r[0],r[1]), __fadd_rn(r[2],r[3])),
            __fadd_rn(__fadd_rn(r[4],r[5]), __fadd_rn(r[6],r[7])));
    }

    // pixel-global kmin over 12 candidates (butterfly within same-li group)
    unsigned kmin = umn(k1, umn(k2, k3));
    kmin = umn(kmin, __shfl_xor(kmin, 16, 64));
    kmin = umn(kmin, __shfl_xor(kmin, 32, 64));
    const float thr = __uint_as_float(kmin & 0xFFFFFE00u) + 1.2e-4f;
    float bd = 3.0e38f; int bj = 1023;

    #define RESCORE(K) do {                                               \
        float da_ = __uint_as_float((K) & 0xFFFFFE00u);                   \
        if (da_ <= thr) {                                                 \
            int j_ = (int)((K) & 511u);                                   \
            const float* er_ = cb + (size_t)j_ * 64;                      \
            float a_ = 0.f;                                               \
            _Pragma("unroll")                                             \
            for (int c_ = 0; c_ < 64; ++c_)                               \
                a_ = __fmaf_rn(zr[c_], er_[c_], a_);                      \
            float dd_ = __fsub_rn(__fadd_rn(ap, eshx[j_]),                \
                                  __fmul_rn(2.0f, a_));                   \
            if (dd_ < bd || (dd_ == bd && j_ < bj)) { bd = dd_; bj = j_; }\
        }                                                                 \
    } while (0)
    RESCORE(k1); RESCORE(k2); RESCORE(k3);
    #undef RESCORE

    // lexicographic (d, j) butterfly merge across the 4 lg groups
    #pragma unroll
    for (int m = 16; m <= 32; m <<= 1) {
        float od = __shfl_xor(bd, m, 64);
        int   oj = __shfl_xor(bj, m, 64);
        if (od < bd || (od == bd && oj < bj)) { bd = od; bj = oj; }
    }
    if (l < 16) {                          // one lane-group writes idx + loss
        out[IDX_OFF + pxw] = (float)bj;
        ls += bd;                          // exact ||z - e_bj||^2 (incl. ap)
    }

    // ---- z_q write: all lanes hold their pixel's bj; lane (cq,li) writes
    // c-planes [cq*16, cq*16+16) for pixel li ----
    {
        const int cq = l >> 4;
        const float* eb = cb + (size_t)bj * 64;
        float* zq = out + ZQ_OFF + (size_t)bb * (C_DIM * HW) + (pxw & (HW - 1));
        #pragma unroll
        for (int cc = 0; cc < 16; ++cc) {
            int c = cq * 16 + cc;
            zq[(size_t)c * HW] = eb[c];    // 16 px x 4 planes per instr
        }
    }

    // ---- loss reduce: wave -> block -> ws ----
    #pragma unroll
    for (int off = 32; off; off >>= 1) ls += __shfl_down(ls, off, 64);
    if (l == 0) wsum[wv] = ls;
    __syncthreads();
    if (t == 0) {
        float s = 0.f;
        #pragma unroll
        for (int i = 0; i < 16; ++i) s += wsum[i];
        ws[blockIdx.x] = s;
    }
}

__global__ __launch_bounds__(256) void vq_loss(
    const float* __restrict__ ws, float* __restrict__ out)
{
    __shared__ float sm[4];
    float v = ws[threadIdx.x] + ws[threadIdx.x + 256];   // 512 partials
    #pragma unroll
    for (int off = 32; off; off >>= 1) v += __shfl_down(v, off, 64);
    const int lane = threadIdx.x & 63, wid = threadIdx.x >> 6;
    if (lane == 0) sm[wid] = v;
    __syncthreads();
    if (threadIdx.x == 0)
        out[0] = ((sm[0] + sm[1]) + (sm[2] + sm[3])) * (1.0f / 8388608.0f);
}

extern "C" void kernel_launch(void* const* d_in, const int* in_sizes, int n_in,
                              void* d_out, int out_size, void* d_ws, size_t ws_size,
                              hipStream_t stream)
{
    const float* z  = (const float*)d_in[0];   // 8388608 f32
    const float* cb = (const float*)d_in[1];   // 32768 f32
    float* out = (float*)d_out;
    float* ws  = (float*)d_ws;                 // 512 f32 partials

    vq_main<<<NBLK, TPB, 0, stream>>>(z, cb, out, ws);
    vq_loss<<<1, 256, 0, stream>>>(ws, out);
}

// Round 17
// 44.272 us; speedup vs baseline: 1.5802x; 1.5802x over previous
//
#include <hip/hip_runtime.h>

// VectorQuantizer on MI355X (gfx950) — single-pass fp16 MFMA scan + exact rescore.
// Round 16: round 15's geometry (1 tile/WAVE -> 8192 waves -> 32 waves/CU
// potential) with __launch_bounds__(1024, 4): min-waves=8 forced a 32-VGPR
// spill regime twice (rounds 13/15: FETCH/WRITE ballooned, dur ~70us); min=4
// gives cap 128 and the allocator's natural 56-64 choice (rounds 12/14, no
// spill). At VGPR<=64 the HW can co-schedule 2x1024-thr blocks/CU (LDS 140KB,
// 8 waves/SIMD) with no allocator coercion. Everything else identical to
// round 15 (outputs bit-identical to rounds 12-15, all passed).

#define C_DIM   64
#define N_EMB   512
#define HW      4096
#define N_PIX   (32 * HW)            // 131072
#define ZQ_OFF  1
#define IDX_OFF (1 + N_PIX * C_DIM)
#define NBLK    512                  // 256 px per block
#define TPB     1024                 // 16 waves x 16 px

typedef _Float16 half8 __attribute__((ext_vector_type(8)));
typedef float    f32x4 __attribute__((ext_vector_type(4)));
union FragH { unsigned u[4]; half8 h8; uint4 u4; _Float16 h[8]; };

__device__ __forceinline__ unsigned umn(unsigned a, unsigned b){ return a<b?a:b; }
__device__ __forceinline__ unsigned med3u(unsigned a, unsigned b, unsigned c){
    unsigned r;
    asm("v_med3_u32 %0, %1, %2, %3" : "=v"(r) : "v"(a), "v"(b), "v"(c));
    return r;
}

__global__ __launch_bounds__(TPB, 4) void vq_main(
    const float* __restrict__ z,
    const float* __restrict__ cb,
    float* __restrict__ out,
    float* __restrict__ ws)
{
    __shared__ unsigned cbh[N_EMB * 32];   // 64KB codebook as fp16 pairs (e*512), swizzled
    __shared__ float    esh5[N_EMB];       // esum + 0.5 (scan keys, positive d)
    __shared__ float    eshx[N_EMB];       // numpy-exact esum (rescore)
    __shared__ float    wsum[16];

    const int t = threadIdx.x;             // 0..1023

    // ---- Stage codebook (threads 0..511: thread t owns code row t) ----
    if (t < N_EMB) {
        const float* e = cb + t * C_DIM;
        float ev[64];
        #pragma unroll
        for (int q = 0; q < 16; ++q) {
            float4 v = ((const float4*)e)[q];
            ev[4*q+0]=v.x; ev[4*q+1]=v.y; ev[4*q+2]=v.z; ev[4*q+3]=v.w;
        }
        // numpy pairwise_sum(n=64): 8 accs, rounded mul, tree combine
        float r[8];
        #pragma unroll
        for (int i = 0; i < 8; ++i) r[i] = __fmul_rn(ev[i], ev[i]);
        #pragma unroll
        for (int k = 8; k < 64; k += 8) {
            #pragma unroll
            for (int i = 0; i < 8; ++i)
                r[i] = __fadd_rn(r[i], __fmul_rn(ev[k+i], ev[k+i]));
        }
        float es = __fadd_rn(
            __fadd_rn(__fadd_rn(r[0],r[1]), __fadd_rn(r[2],r[3])),
            __fadd_rn(__fadd_rn(r[4],r[5]), __fadd_rn(r[6],r[7])));
        eshx[t] = es;
        esh5[t] = es + 0.5f;
        unsigned hw_[32];
        #pragma unroll
        for (int w2 = 0; w2 < 32; ++w2) {
            union { _Float16 h[2]; unsigned u; } pk;
            pk.h[0] = (_Float16)(ev[2*w2]   * 512.0f);
            pk.h[1] = (_Float16)(ev[2*w2+1] * 512.0f);
            hw_[w2] = pk.u;
        }
        const int rs = t & 7;
        #pragma unroll
        for (int g = 0; g < 8; ++g) {
            int g2 = g ^ rs;
            *(uint4*)&cbh[t*32 + g2*4] =
                make_uint4(hw_[4*g], hw_[4*g+1], hw_[4*g+2], hw_[4*g+3]);
        }
    }
    __syncthreads();

    const int l   = t & 63;
    const int wv  = t >> 6;                // wave 0..15
    const int lg  = l >> 4;                // k-chunk / candidate group 0..3
    const int li  = l & 15;                // pixel col / code row in tile
    const int bb  = blockIdx.x >> 4;       // batch (256 px per block, 4096 per b)
    const int g20 = (lg)     ^ (li & 7);   // swizzled granule, k-step 0
    const int g21 = (4 + lg) ^ (li & 7);   // swizzled granule, k-step 1
    const int jb  = lg * 4;
    float ls = 0.f;

    // ---- This wave's single 16-px tile; lane's pixel = base + li ----
    const int pxw = blockIdx.x * 256 + wv * 16 + li;
    const float* zb = z + (size_t)bb * (C_DIM * HW) + (pxw & (HW - 1));

    // B-fragments: z as fp16, lane supplies c = s*32 + lg*8 + i
    FragH b0, b1;
    {
        const float* c0 = zb + (size_t)(lg*8) * HW;
        const float* c1 = zb + (size_t)(32 + lg*8) * HW;
        #pragma unroll
        for (int i = 0; i < 8; ++i) {
            b0.h[i] = (_Float16)c0[(size_t)i*HW];
            b1.h[i] = (_Float16)c1[(size_t)i*HW];
        }
    }

    // ---- MFMA scan: 32 code-tiles; per-lane top-3 keys (med3 insert) ----
    unsigned k1 = 0xFFFFFFFFu, k2 = 0xFFFFFFFFu, k3 = 0xFFFFFFFFu;
    #pragma unroll 4
    for (int T = 0; T < 32; ++T) {
        const int row = T*16 + li;
        FragH a0, a1;
        a0.u4 = *(const uint4*)&cbh[row*32 + g20*4];
        a1.u4 = *(const uint4*)&cbh[row*32 + g21*4];
        f32x4 es = *(const f32x4*)&esh5[T*16 + jb];
        f32x4 acc = {0.f,0.f,0.f,0.f};
        acc = __builtin_amdgcn_mfma_f32_16x16x32_f16(a0.h8, b0.h8, acc, 0,0,0);
        acc = __builtin_amdgcn_mfma_f32_16x16x32_f16(a1.h8, b1.h8, acc, 0,0,0);
        const int jT = T*16 + jb;
        #pragma unroll
        for (int r2 = 0; r2 < 4; ++r2) {
            float d = __fmaf_rn(-0.00390625f, acc[r2], es[r2]);   // >0 -> sortable
            unsigned key = (__float_as_uint(d) & 0xFFFFFE00u) | (unsigned)(jT + r2);
            unsigned nk3 = med3u(key, k2, k3);     // top-3 insert: 3 ops
            unsigned nk2 = med3u(key, k1, k2);
            k1 = umn(k1, key); k2 = nk2; k3 = nk3;
        }
    }

    // ---- rescore: every lane handles its own 3 candidates (no handoff) ----
    // zr reload: 4-way lane broadcast (lanes lg0-3 share li -> same address)
    float zr[64];
    #pragma unroll
    for (int c = 0; c < 64; ++c) zr[c] = zb[(size_t)c * HW];
    float ap;
    {   // numpy-exact ||z||^2
        float r[8];
        #pragma unroll
        for (int i = 0; i < 8; ++i) r[i] = __fmul_rn(zr[i], zr[i]);
        #pragma unroll
        for (int k = 8; k < 64; k += 8) {
            #pragma unroll
            for (int i = 0; i < 8; ++i)
                r[i] = __fadd_rn(r[i], __fmul_rn(zr[k+i], zr[k+i]));
        }
        ap = __fadd_rn(
            __fadd_rn(__fadd_rn(r[0],r[1]), __fadd_rn(r[2],r[3])),
            __fadd_rn(__fadd_rn(r[4],r[5]), __fadd_rn(r[6],r[7])));
    }

    // pixel-global kmin over 12 candidates (butterfly within same-li group)
    unsigned kmin = umn(k1, umn(k2, k3));
    kmin = umn(kmin, __shfl_xor(kmin, 16, 64));
    kmin = umn(kmin, __shfl_xor(kmin, 32, 64));
    const float thr = __uint_as_float(kmin & 0xFFFFFE00u) + 1.2e-4f;
    float bd = 3.0e38f; int bj = 1023;

    #define RESCORE(K) do {                                               \
        float da_ = __uint_as_float((K) & 0xFFFFFE00u);                   \
        if (da_ <= thr) {                                                 \
            int j_ = (int)((K) & 511u);                                   \
            const float* er_ = cb + (size_t)j_ * 64;                      \
            float a_ = 0.f;                                               \
            _Pragma("unroll")                                             \
            for (int c_ = 0; c_ < 64; ++c_)                               \
                a_ = __fmaf_rn(zr[c_], er_[c_], a_);                      \
            float dd_ = __fsub_rn(__fadd_rn(ap, eshx[j_]),                \
                                  __fmul_rn(2.0f, a_));                   \
            if (dd_ < bd || (dd_ == bd && j_ < bj)) { bd = dd_; bj = j_; }\
        }                                                                 \
    } while (0)
    RESCORE(k1); RESCORE(k2); RESCORE(k3);
    #undef RESCORE

    // lexicographic (d, j) butterfly merge across the 4 lg groups
    #pragma unroll
    for (int m = 16; m <= 32; m <<= 1) {
        float od = __shfl_xor(bd, m, 64);
        int   oj = __shfl_xor(bj, m, 64);
        if (od < bd || (od == bd && oj < bj)) { bd = od; bj = oj; }
    }
    if (l < 16) {                          // one lane-group writes idx + loss
        out[IDX_OFF + pxw] = (float)bj;
        ls += bd;                          // exact ||z - e_bj||^2 (incl. ap)
    }

    // ---- z_q write: all lanes hold their pixel's bj; lane (cq,li) writes
    // c-planes [cq*16, cq*16+16) for pixel li ----
    {
        const int cq = l >> 4;
        const float* eb = cb + (size_t)bj * 64;
        float* zq = out + ZQ_OFF + (size_t)bb * (C_DIM * HW) + (pxw & (HW - 1));
        #pragma unroll
        for (int cc = 0; cc < 16; ++cc) {
            int c = cq * 16 + cc;
            zq[(size_t)c * HW] = eb[c];    // 16 px x 4 planes per instr
        }
    }

    // ---- loss reduce: wave -> block -> ws ----
    #pragma unroll
    for (int off = 32; off; off >>= 1) ls += __shfl_down(ls, off, 64);
    if (l == 0) wsum[wv] = ls;
    __syncthreads();
    if (t == 0) {
        float s = 0.f;
        #pragma unroll
        for (int i = 0; i < 16; ++i) s += wsum[i];
        ws[blockIdx.x] = s;
    }
}

__global__ __launch_bounds__(256) void vq_loss(
    const float* __restrict__ ws, float* __restrict__ out)
{
    __shared__ float sm[4];
    float v = ws[threadIdx.x] + ws[threadIdx.x + 256];   // 512 partials
    #pragma unroll
    for (int off = 32; off; off >>= 1) v += __shfl_down(v, off, 64);
    const int lane = threadIdx.x & 63, wid = threadIdx.x >> 6;
    if (lane == 0) sm[wid] = v;
    __syncthreads();
    if (threadIdx.x == 0)
        out[0] = ((sm[0] + sm[1]) + (sm[2] + sm[3])) * (1.0f / 8388608.0f);
}

extern "C" void kernel_launch(void* const* d_in, const int* in_sizes, int n_in,
                              void* d_out, int out_size, void* d_ws, size_t ws_size,
                              hipStream_t stream)
{
    const float* z  = (const float*)d_in[0];   // 8388608 f32
    const float* cb = (const float*)d_in[1];   // 32768 f32
    float* out = (float*)d_out;
    float* ws  = (float*)d_ws;                 // 512 f32 partials

    vq_main<<<NBLK, TPB, 0, stream>>>(z, cb, out, ws);
    vq_loss<<<1, 256, 0, stream>>>(ws, out);
}